// Round 1
// baseline (1394.439 us; speedup 1.0000x reference)
//
#include <hip/hip_runtime.h>
#include <cstdint>
#include <cstddef>

#define T_DIM 8192
#define H_DIM 1024
#define I_DIM 3584
#define E_DIM 8

typedef __attribute__((ext_vector_type(4))) float f32x4;
typedef __attribute__((ext_vector_type(8))) __bf16 bf16x8;
typedef __attribute__((ext_vector_type(8))) unsigned short u16x8;
typedef __attribute__((ext_vector_type(4))) unsigned short u16x4;

// fp32 -> bf16 round-to-nearest-even (finite inputs)
static __device__ inline unsigned short f2b(float f) {
    unsigned int u = __builtin_bit_cast(unsigned int, f);
    u += 0x7FFFu + ((u >> 16) & 1u);
    return (unsigned short)(u >> 16);
}

static __device__ inline bf16x8 ldfrag(const unsigned short* p) {
    return __builtin_bit_cast(bf16x8, *(const u16x8*)p);
}

// ---------------- router: 1 wave per token ----------------
__global__ __launch_bounds__(256) void router_kernel(
    const float* __restrict__ x, const float* __restrict__ gw,
    const float* __restrict__ gb, int* __restrict__ counts,
    int* __restrict__ tok_exp, float* __restrict__ tok_w)
{
    const int t = blockIdx.x * 4 + (threadIdx.x >> 6);
    const int lane = threadIdx.x & 63;
    const float* xp = x + (size_t)t * H_DIM;
    float xr[16];
#pragma unroll
    for (int i = 0; i < 16; i++) xr[i] = xp[lane + 64 * i];
    float lg[E_DIM];
#pragma unroll
    for (int e = 0; e < E_DIM; e++) {
        const float* gp = gw + e * H_DIM;
        float s = 0.f;
#pragma unroll
        for (int i = 0; i < 16; i++) s += xr[i] * gp[lane + 64 * i];
        for (int off = 32; off; off >>= 1) s += __shfl_xor(s, off, 64);
        lg[e] = s + gb[e];
    }
    if (lane == 0) {
        float mx = lg[0];
#pragma unroll
        for (int e = 1; e < E_DIM; e++) mx = fmaxf(mx, lg[e]);
        float p[E_DIM], sum = 0.f;
#pragma unroll
        for (int e = 0; e < E_DIM; e++) { p[e] = __expf(lg[e] - mx); sum += p[e]; }
        float inv = 1.0f / sum;
        int e0 = 0; float p0 = p[0];
#pragma unroll
        for (int e = 1; e < E_DIM; e++) if (p[e] > p0) { p0 = p[e]; e0 = e; }
        int e1 = -1; float p1 = -1.0f;
#pragma unroll
        for (int e = 0; e < E_DIM; e++) if (e != e0 && p[e] > p1) { p1 = p[e]; e1 = e; }
        tok_exp[t * 2]     = e0;
        tok_exp[t * 2 + 1] = e1;
        tok_w[t * 2]     = p0 * inv;
        tok_w[t * 2 + 1] = p1 * inv;
        atomicAdd(&counts[e0], 1);
        atomicAdd(&counts[e1], 1);
    }
}

// ---------------- exclusive scan over 8 counts ----------------
__global__ void scan_kernel(const int* __restrict__ counts,
                            int* __restrict__ offs, int* __restrict__ wptr)
{
    if (threadIdx.x == 0 && blockIdx.x == 0) {
        int acc = 0;
        for (int e = 0; e < E_DIM; e++) { offs[e] = acc; wptr[e] = acc; acc += counts[e]; }
        offs[E_DIM] = acc;
    }
}

// ---------------- gather tokens into per-expert contiguous bf16 rows ----------------
__global__ __launch_bounds__(256) void gather_kernel(
    const float* __restrict__ x, const int* __restrict__ tok_exp,
    int* __restrict__ wptr, int* __restrict__ tok_row,
    unsigned short* __restrict__ Xg)
{
    const int t = blockIdx.x;
    __shared__ int rows[2];
    if (threadIdx.x < 2) {
        int e = tok_exp[t * 2 + threadIdx.x];
        int r = atomicAdd(&wptr[e], 1);
        rows[threadIdx.x] = r;
        tok_row[t * 2 + threadIdx.x] = r;
    }
    __syncthreads();
    const int c = threadIdx.x * 4;
    f32x4 v = *(const f32x4*)(x + (size_t)t * H_DIM + c);
    u16x4 b;
    b[0] = f2b(v[0]); b[1] = f2b(v[1]); b[2] = f2b(v[2]); b[3] = f2b(v[3]);
    *(u16x4*)&Xg[(size_t)rows[0] * H_DIM + c] = b;
    *(u16x4*)&Xg[(size_t)rows[1] * H_DIM + c] = b;
}

// ---------------- GEMM1: Hg = silu(Xg @ w1^T) * (Xg @ w3^T), per expert ----------------
// 64x64 tile per 256-thread block; wave quadrants of 32x32 via 2x2 16x16x32 MFMA.
__global__ __launch_bounds__(256) void gemm13_kernel(
    const unsigned short* __restrict__ Xg, const float* __restrict__ w1,
    const float* __restrict__ w3, const int* __restrict__ offs,
    unsigned short* __restrict__ Hg)
{
    const int e = blockIdx.z;
    const int base = offs[e];
    const int Me = offs[e + 1] - base;
    const int m0 = blockIdx.y * 64;
    if (m0 >= Me) return;
    const int n0 = blockIdx.x * 64;
    const int tid = threadIdx.x;

    __shared__ __align__(16) unsigned short As[64][40];
    __shared__ __align__(16) unsigned short B1s[64][40];
    __shared__ __align__(16) unsigned short B3s[64][40];

    const int lane = tid & 63;
    const int wv = tid >> 6;
    const int wm = wv & 1, wn = wv >> 1;
    const int frow = lane & 15;        // A-row / B-row / C-col within 16
    const int koff = (lane >> 4) * 8;  // k offset within 32

    f32x4 acc1[2][2], acc3[2][2];
#pragma unroll
    for (int i = 0; i < 2; i++)
#pragma unroll
        for (int j = 0; j < 2; j++) {
            acc1[i][j] = f32x4{0.f, 0.f, 0.f, 0.f};
            acc3[i][j] = f32x4{0.f, 0.f, 0.f, 0.f};
        }

    const int srow = tid >> 2;         // 0..63
    const int sc = (tid & 3) * 8;      // 0,8,16,24
    const size_t w1base = (size_t)e * I_DIM * H_DIM + (size_t)(n0 + srow) * H_DIM;
    const size_t abase = (size_t)(base + m0 + srow) * H_DIM;

    for (int kk = 0; kk < H_DIM; kk += 32) {
        // stage A (already bf16)
        *(uint4*)&As[srow][sc] = *(const uint4*)(Xg + abase + kk + sc);
        // stage B1/B3 (fp32 -> bf16)
        {
            f32x4 f0 = *(const f32x4*)(w1 + w1base + kk + sc);
            f32x4 f1 = *(const f32x4*)(w1 + w1base + kk + sc + 4);
            u16x8 b;
            b[0] = f2b(f0[0]); b[1] = f2b(f0[1]); b[2] = f2b(f0[2]); b[3] = f2b(f0[3]);
            b[4] = f2b(f1[0]); b[5] = f2b(f1[1]); b[6] = f2b(f1[2]); b[7] = f2b(f1[3]);
            *(u16x8*)&B1s[srow][sc] = b;
        }
        {
            f32x4 f0 = *(const f32x4*)(w3 + w1base + kk + sc);
            f32x4 f1 = *(const f32x4*)(w3 + w1base + kk + sc + 4);
            u16x8 b;
            b[0] = f2b(f0[0]); b[1] = f2b(f0[1]); b[2] = f2b(f0[2]); b[3] = f2b(f0[3]);
            b[4] = f2b(f1[0]); b[5] = f2b(f1[1]); b[6] = f2b(f1[2]); b[7] = f2b(f1[3]);
            *(u16x8*)&B3s[srow][sc] = b;
        }
        __syncthreads();

        bf16x8 a0  = ldfrag(&As [wm * 32 +  0 + frow][koff]);
        bf16x8 a1  = ldfrag(&As [wm * 32 + 16 + frow][koff]);
        bf16x8 b10 = ldfrag(&B1s[wn * 32 +  0 + frow][koff]);
        bf16x8 b11 = ldfrag(&B1s[wn * 32 + 16 + frow][koff]);
        bf16x8 b30 = ldfrag(&B3s[wn * 32 +  0 + frow][koff]);
        bf16x8 b31 = ldfrag(&B3s[wn * 32 + 16 + frow][koff]);

        acc1[0][0] = __builtin_amdgcn_mfma_f32_16x16x32_bf16(a0, b10, acc1[0][0], 0, 0, 0);
        acc1[0][1] = __builtin_amdgcn_mfma_f32_16x16x32_bf16(a0, b11, acc1[0][1], 0, 0, 0);
        acc1[1][0] = __builtin_amdgcn_mfma_f32_16x16x32_bf16(a1, b10, acc1[1][0], 0, 0, 0);
        acc1[1][1] = __builtin_amdgcn_mfma_f32_16x16x32_bf16(a1, b11, acc1[1][1], 0, 0, 0);
        acc3[0][0] = __builtin_amdgcn_mfma_f32_16x16x32_bf16(a0, b30, acc3[0][0], 0, 0, 0);
        acc3[0][1] = __builtin_amdgcn_mfma_f32_16x16x32_bf16(a0, b31, acc3[0][1], 0, 0, 0);
        acc3[1][0] = __builtin_amdgcn_mfma_f32_16x16x32_bf16(a1, b30, acc3[1][0], 0, 0, 0);
        acc3[1][1] = __builtin_amdgcn_mfma_f32_16x16x32_bf16(a1, b31, acc3[1][1], 0, 0, 0);
        __syncthreads();
    }

    // epilogue: SwiGLU, write bf16
#pragma unroll
    for (int im = 0; im < 2; im++) {
        const int rb = m0 + wm * 32 + im * 16 + (lane >> 4) * 4;
#pragma unroll
        for (int jn = 0; jn < 2; jn++) {
            const int cb = n0 + wn * 32 + jn * 16 + frow;
            f32x4 v1 = acc1[im][jn], v3 = acc3[im][jn];
#pragma unroll
            for (int r = 0; r < 4; r++) {
                const int row = rb + r;
                if (row < Me) {
                    float xx = v1[r];
                    float h = (xx / (1.0f + __expf(-xx))) * v3[r];
                    Hg[(size_t)(base + row) * I_DIM + cb] = f2b(h);
                }
            }
        }
    }
}

// ---------------- GEMM2: Og = Hg @ w2^T, per expert ----------------
__global__ __launch_bounds__(256) void gemm2_kernel(
    const unsigned short* __restrict__ Hg, const float* __restrict__ w2,
    const int* __restrict__ offs, float* __restrict__ Og)
{
    const int e = blockIdx.z;
    const int base = offs[e];
    const int Me = offs[e + 1] - base;
    const int m0 = blockIdx.y * 64;
    if (m0 >= Me) return;
    const int n0 = blockIdx.x * 64;
    const int tid = threadIdx.x;

    __shared__ __align__(16) unsigned short As[64][40];
    __shared__ __align__(16) unsigned short Bs[64][40];

    const int lane = tid & 63;
    const int wv = tid >> 6;
    const int wm = wv & 1, wn = wv >> 1;
    const int frow = lane & 15;
    const int koff = (lane >> 4) * 8;

    f32x4 acc[2][2];
#pragma unroll
    for (int i = 0; i < 2; i++)
#pragma unroll
        for (int j = 0; j < 2; j++) acc[i][j] = f32x4{0.f, 0.f, 0.f, 0.f};

    const int srow = tid >> 2;
    const int sc = (tid & 3) * 8;
    const size_t wbase = (size_t)e * H_DIM * I_DIM + (size_t)(n0 + srow) * I_DIM;
    const size_t abase = (size_t)(base + m0 + srow) * I_DIM;

    for (int kk = 0; kk < I_DIM; kk += 32) {
        *(uint4*)&As[srow][sc] = *(const uint4*)(Hg + abase + kk + sc);
        {
            f32x4 f0 = *(const f32x4*)(w2 + wbase + kk + sc);
            f32x4 f1 = *(const f32x4*)(w2 + wbase + kk + sc + 4);
            u16x8 b;
            b[0] = f2b(f0[0]); b[1] = f2b(f0[1]); b[2] = f2b(f0[2]); b[3] = f2b(f0[3]);
            b[4] = f2b(f1[0]); b[5] = f2b(f1[1]); b[6] = f2b(f1[2]); b[7] = f2b(f1[3]);
            *(u16x8*)&Bs[srow][sc] = b;
        }
        __syncthreads();

        bf16x8 a0 = ldfrag(&As[wm * 32 +  0 + frow][koff]);
        bf16x8 a1 = ldfrag(&As[wm * 32 + 16 + frow][koff]);
        bf16x8 b0 = ldfrag(&Bs[wn * 32 +  0 + frow][koff]);
        bf16x8 b1 = ldfrag(&Bs[wn * 32 + 16 + frow][koff]);

        acc[0][0] = __builtin_amdgcn_mfma_f32_16x16x32_bf16(a0, b0, acc[0][0], 0, 0, 0);
        acc[0][1] = __builtin_amdgcn_mfma_f32_16x16x32_bf16(a0, b1, acc[0][1], 0, 0, 0);
        acc[1][0] = __builtin_amdgcn_mfma_f32_16x16x32_bf16(a1, b0, acc[1][0], 0, 0, 0);
        acc[1][1] = __builtin_amdgcn_mfma_f32_16x16x32_bf16(a1, b1, acc[1][1], 0, 0, 0);
        __syncthreads();
    }

#pragma unroll
    for (int im = 0; im < 2; im++) {
        const int rb = m0 + wm * 32 + im * 16 + (lane >> 4) * 4;
#pragma unroll
        for (int jn = 0; jn < 2; jn++) {
            const int cb = n0 + wn * 32 + jn * 16 + frow;
            f32x4 v = acc[im][jn];
#pragma unroll
            for (int r = 0; r < 4; r++) {
                const int row = rb + r;
                if (row < Me) Og[(size_t)(base + row) * H_DIM + cb] = v[r];
            }
        }
    }
}

// ---------------- combine: out[t] = p0*Og[r0] + p1*Og[r1] ----------------
__global__ __launch_bounds__(256) void combine_kernel(
    const float* __restrict__ Og, const int* __restrict__ tok_row,
    const float* __restrict__ tok_w, float* __restrict__ out)
{
    const int t = blockIdx.x;          // one block per token (H/4 == 256 lanes)
    const int c = threadIdx.x * 4;
    const int r0 = tok_row[t * 2], r1 = tok_row[t * 2 + 1];
    const float w0 = tok_w[t * 2], w1 = tok_w[t * 2 + 1];
    f32x4 a = *(const f32x4*)(Og + (size_t)r0 * H_DIM + c);
    f32x4 b = *(const f32x4*)(Og + (size_t)r1 * H_DIM + c);
    f32x4 o = a * w0 + b * w1;
    *(f32x4*)(out + (size_t)t * H_DIM + c) = o;
}

extern "C" void kernel_launch(void* const* d_in, const int* in_sizes, int n_in,
                              void* d_out, int out_size, void* d_ws, size_t ws_size,
                              hipStream_t stream) {
    const float* x  = (const float*)d_in[0];
    const float* gw = (const float*)d_in[1];
    const float* gb = (const float*)d_in[2];
    const float* w1 = (const float*)d_in[3];
    const float* w2 = (const float*)d_in[4];
    const float* w3 = (const float*)d_in[5];
    float* out = (float*)d_out;

    char* ws = (char*)d_ws;
    int* counts  = (int*)ws;                 // 8
    int* wptr    = counts + 8;               // 8
    int* offs    = wptr + 8;                 // 9
    int* tok_exp = (int*)(ws + 256);         // 2T
    int* tok_row = tok_exp + 2 * T_DIM;      // 2T
    float* tok_w = (float*)(tok_row + 2 * T_DIM); // 2T
    size_t ofs = 256 + (size_t)3 * 2 * T_DIM * 4;
    ofs = (ofs + 255) & ~(size_t)255;
    const size_t ROWS = 2 * T_DIM + 64;      // 64 rows slack for tile overshoot
    unsigned short* Xg = (unsigned short*)(ws + ofs); ofs += ROWS * H_DIM * 2;
    unsigned short* Hg = (unsigned short*)(ws + ofs); ofs += ROWS * I_DIM * 2;
    float* Og = (float*)(ws + ofs);                   ofs += ROWS * H_DIM * 4;

    hipMemsetAsync(counts, 0, 64, stream);
    router_kernel<<<T_DIM / 4, 256, 0, stream>>>(x, gw, gb, counts, tok_exp, tok_w);
    scan_kernel<<<1, 64, 0, stream>>>(counts, offs, wptr);
    gather_kernel<<<T_DIM, 256, 0, stream>>>(x, tok_exp, wptr, tok_row, Xg);
    gemm13_kernel<<<dim3(I_DIM / 64, T_DIM / 64, E_DIM), 256, 0, stream>>>(Xg, w1, w3, offs, Hg);
    gemm2_kernel<<<dim3(H_DIM / 64, T_DIM / 64, E_DIM), 256, 0, stream>>>(Hg, w2, offs, Og);
    combine_kernel<<<T_DIM, 256, 0, stream>>>(Og, tok_row, tok_w, out);
}

// Round 2
// 1241.359 us; speedup vs baseline: 1.1233x; 1.1233x over previous
//
#include <hip/hip_runtime.h>
#include <cstdint>
#include <cstddef>

#define T_DIM 8192
#define H_DIM 1024
#define I_DIM 3584
#define E_DIM 8
#define BK 32

typedef __attribute__((ext_vector_type(4))) float f32x4;
typedef __attribute__((ext_vector_type(8))) __bf16 bf16x8;
typedef __attribute__((ext_vector_type(8))) unsigned short u16x8;
typedef __attribute__((ext_vector_type(4))) unsigned short u16x4;

// fp32 -> bf16 round-to-nearest-even (finite inputs)
static __device__ inline unsigned short f2b(float f) {
    unsigned int u = __builtin_bit_cast(unsigned int, f);
    u += 0x7FFFu + ((u >> 16) & 1u);
    return (unsigned short)(u >> 16);
}

static __device__ inline bf16x8 ldfrag(const unsigned short* p) {
    return __builtin_bit_cast(bf16x8, *(const u16x8*)p);
}

// async global->LDS, 16B per lane. LDS dest is wave-uniform base + lane*16 (HW rule).
static __device__ inline void glds16(const unsigned short* g, unsigned short* l) {
    __builtin_amdgcn_global_load_lds(
        (const __attribute__((address_space(1))) void*)g,
        (__attribute__((address_space(3))) void*)l,
        16, 0, 0);
}

// ---------------- weight fp32 -> bf16, one pass ----------------
__global__ __launch_bounds__(256) void convert_kernel(
    const float* __restrict__ src, unsigned short* __restrict__ dst, long n)
{
    long i = ((long)blockIdx.x * 256 + threadIdx.x) * 8;
    if (i >= n) return;
    f32x4 f0 = *(const f32x4*)(src + i);
    f32x4 f1 = *(const f32x4*)(src + i + 4);
    u16x8 b;
    b[0] = f2b(f0[0]); b[1] = f2b(f0[1]); b[2] = f2b(f0[2]); b[3] = f2b(f0[3]);
    b[4] = f2b(f1[0]); b[5] = f2b(f1[1]); b[6] = f2b(f1[2]); b[7] = f2b(f1[3]);
    *(u16x8*)(dst + i) = b;
}

// ---------------- router: 1 wave per token ----------------
__global__ __launch_bounds__(256) void router_kernel(
    const float* __restrict__ x, const float* __restrict__ gw,
    const float* __restrict__ gb, int* __restrict__ counts,
    int* __restrict__ tok_exp, float* __restrict__ tok_w)
{
    const int t = blockIdx.x * 4 + (threadIdx.x >> 6);
    const int lane = threadIdx.x & 63;
    const float* xp = x + (size_t)t * H_DIM;
    float xr[16];
#pragma unroll
    for (int i = 0; i < 16; i++) xr[i] = xp[lane + 64 * i];
    float lg[E_DIM];
#pragma unroll
    for (int e = 0; e < E_DIM; e++) {
        const float* gp = gw + e * H_DIM;
        float s = 0.f;
#pragma unroll
        for (int i = 0; i < 16; i++) s += xr[i] * gp[lane + 64 * i];
        for (int off = 32; off; off >>= 1) s += __shfl_xor(s, off, 64);
        lg[e] = s + gb[e];
    }
    if (lane == 0) {
        float mx = lg[0];
#pragma unroll
        for (int e = 1; e < E_DIM; e++) mx = fmaxf(mx, lg[e]);
        float p[E_DIM], sum = 0.f;
#pragma unroll
        for (int e = 0; e < E_DIM; e++) { p[e] = __expf(lg[e] - mx); sum += p[e]; }
        float inv = 1.0f / sum;
        int e0 = 0; float p0 = p[0];
#pragma unroll
        for (int e = 1; e < E_DIM; e++) if (p[e] > p0) { p0 = p[e]; e0 = e; }
        int e1 = -1; float p1 = -1.0f;
#pragma unroll
        for (int e = 0; e < E_DIM; e++) if (e != e0 && p[e] > p1) { p1 = p[e]; e1 = e; }
        tok_exp[t * 2]     = e0;
        tok_exp[t * 2 + 1] = e1;
        tok_w[t * 2]     = p0 * inv;
        tok_w[t * 2 + 1] = p1 * inv;
        atomicAdd(&counts[e0], 1);
        atomicAdd(&counts[e1], 1);
    }
}

// ---------------- exclusive scan over 8 counts ----------------
__global__ void scan_kernel(const int* __restrict__ counts,
                            int* __restrict__ offs, int* __restrict__ wptr)
{
    if (threadIdx.x == 0 && blockIdx.x == 0) {
        int acc = 0;
        for (int e = 0; e < E_DIM; e++) { offs[e] = acc; wptr[e] = acc; acc += counts[e]; }
        offs[E_DIM] = acc;
    }
}

// ---------------- gather tokens into per-expert contiguous bf16 rows ----------------
__global__ __launch_bounds__(256) void gather_kernel(
    const float* __restrict__ x, const int* __restrict__ tok_exp,
    int* __restrict__ wptr, int* __restrict__ tok_row,
    unsigned short* __restrict__ Xg)
{
    const int t = blockIdx.x;
    __shared__ int rows[2];
    if (threadIdx.x < 2) {
        int e = tok_exp[t * 2 + threadIdx.x];
        int r = atomicAdd(&wptr[e], 1);
        rows[threadIdx.x] = r;
        tok_row[t * 2 + threadIdx.x] = r;
    }
    __syncthreads();
    const int c = threadIdx.x * 4;
    f32x4 v = *(const f32x4*)(x + (size_t)t * H_DIM + c);
    u16x4 b;
    b[0] = f2b(v[0]); b[1] = f2b(v[1]); b[2] = f2b(v[2]); b[3] = f2b(v[3]);
    *(u16x4*)&Xg[(size_t)rows[0] * H_DIM + c] = b;
    *(u16x4*)&Xg[(size_t)rows[1] * H_DIM + c] = b;
}

// ---------------- GEMM1: Hg = silu(Xg @ w1^T) * (Xg @ w3^T) ----------------
// m97 structure: 128M x 64N tile (dual accumulators = 128x128-equivalent MFMA density),
// BK=32, unpadded LDS, global_load_lds width=16 staging.
__global__ __launch_bounds__(256) void gemm13_kernel(
    const unsigned short* __restrict__ Xg, const unsigned short* __restrict__ w1b,
    const unsigned short* __restrict__ w3b, const int* __restrict__ offs,
    unsigned short* __restrict__ Hg)
{
    const int e = blockIdx.z;
    const int base = offs[e];
    const int Me = offs[e + 1] - base;
    const int m0 = blockIdx.y * 128;
    if (m0 >= Me) return;
    const int n0 = blockIdx.x * 64;
    const int tid = threadIdx.x;
    const int lane = tid & 63;
    const int wv = tid >> 6;

    __shared__ __align__(16) unsigned short As[128 * BK];
    __shared__ __align__(16) unsigned short B1s[64 * BK];
    __shared__ __align__(16) unsigned short B3s[64 * BK];

    const int wm = wv & 1;            // M half (64 rows)
    const int wn = wv >> 1;           // N half (32 cols)
    const int frow = lane & 15;
    const int koff = (lane >> 4) * 8;

    f32x4 acc1[4][2], acc3[4][2];
#pragma unroll
    for (int i = 0; i < 4; i++)
#pragma unroll
        for (int j = 0; j < 2; j++) {
            acc1[i][j] = f32x4{0.f, 0.f, 0.f, 0.f};
            acc3[i][j] = f32x4{0.f, 0.f, 0.f, 0.f};
        }

    // staging addresses: one glds16 covers 16 rows x 32 cols (1 KiB)
    const int lrow = lane >> 2;              // 0..15
    const int lcol = (lane & 3) * 8;         // 0,8,16,24
    const int ar0 = (wv * 2) * 16 + lrow;    // A rows: instr pair per wave
    const int ar1 = (wv * 2 + 1) * 16 + lrow;
    const int br  = wv * 16 + lrow;          // B rows: one instr per wave
    const unsigned short* Ag0 = Xg + (size_t)(base + m0 + ar0) * H_DIM + lcol;
    const unsigned short* Ag1 = Xg + (size_t)(base + m0 + ar1) * H_DIM + lcol;
    const size_t wb = (size_t)e * I_DIM * H_DIM + (size_t)(n0 + br) * H_DIM + lcol;
    const unsigned short* B1g = w1b + wb;
    const unsigned short* B3g = w3b + wb;
    unsigned short* AsD0 = &As[(wv * 2) * 16 * BK];
    unsigned short* AsD1 = &As[(wv * 2 + 1) * 16 * BK];
    unsigned short* B1D = &B1s[wv * 16 * BK];
    unsigned short* B3D = &B3s[wv * 16 * BK];

    for (int kk = 0; kk < H_DIM; kk += BK) {
        glds16(Ag0 + kk, AsD0);
        glds16(Ag1 + kk, AsD1);
        glds16(B1g + kk, B1D);
        glds16(B3g + kk, B3D);
        __syncthreads();

        bf16x8 a[4], b1[2], b3[2];
#pragma unroll
        for (int im = 0; im < 4; im++)
            a[im] = ldfrag(&As[(wm * 64 + im * 16 + frow) * BK + koff]);
#pragma unroll
        for (int jn = 0; jn < 2; jn++) {
            b1[jn] = ldfrag(&B1s[(wn * 32 + jn * 16 + frow) * BK + koff]);
            b3[jn] = ldfrag(&B3s[(wn * 32 + jn * 16 + frow) * BK + koff]);
        }
#pragma unroll
        for (int im = 0; im < 4; im++)
#pragma unroll
            for (int jn = 0; jn < 2; jn++) {
                acc1[im][jn] = __builtin_amdgcn_mfma_f32_16x16x32_bf16(a[im], b1[jn], acc1[im][jn], 0, 0, 0);
                acc3[im][jn] = __builtin_amdgcn_mfma_f32_16x16x32_bf16(a[im], b3[jn], acc3[im][jn], 0, 0, 0);
            }
        __syncthreads();
    }

    // epilogue: SwiGLU, bf16 store (C layout: col=lane&15, row=(lane>>4)*4+r)
#pragma unroll
    for (int im = 0; im < 4; im++) {
        const int rb = m0 + wm * 64 + im * 16 + (lane >> 4) * 4;
#pragma unroll
        for (int jn = 0; jn < 2; jn++) {
            const int cb = n0 + wn * 32 + jn * 16 + frow;
            f32x4 v1 = acc1[im][jn], v3 = acc3[im][jn];
#pragma unroll
            for (int r = 0; r < 4; r++) {
                const int row = rb + r;
                if (row < Me) {
                    float xx = v1[r];
                    float h = (xx / (1.0f + __expf(-xx))) * v3[r];
                    Hg[(size_t)(base + row) * I_DIM + cb] = f2b(h);
                }
            }
        }
    }
}

// ---------------- GEMM2: Og = Hg @ w2^T (m97 structure, 128x128 tile) ----------------
__global__ __launch_bounds__(256) void gemm2_kernel(
    const unsigned short* __restrict__ Hg, const unsigned short* __restrict__ w2b,
    const int* __restrict__ offs, float* __restrict__ Og)
{
    const int e = blockIdx.z;
    const int base = offs[e];
    const int Me = offs[e + 1] - base;
    const int m0 = blockIdx.y * 128;
    if (m0 >= Me) return;
    const int n0 = blockIdx.x * 128;
    const int tid = threadIdx.x;
    const int lane = tid & 63;
    const int wv = tid >> 6;

    __shared__ __align__(16) unsigned short As[128 * BK];
    __shared__ __align__(16) unsigned short Bs[128 * BK];

    const int wm = wv & 1;
    const int wn = wv >> 1;
    const int frow = lane & 15;
    const int koff = (lane >> 4) * 8;

    f32x4 acc[4][4];
#pragma unroll
    for (int i = 0; i < 4; i++)
#pragma unroll
        for (int j = 0; j < 4; j++) acc[i][j] = f32x4{0.f, 0.f, 0.f, 0.f};

    const int lrow = lane >> 2;
    const int lcol = (lane & 3) * 8;
    const int r0 = (wv * 2) * 16 + lrow;
    const int r1 = (wv * 2 + 1) * 16 + lrow;
    const unsigned short* Ag0 = Hg + (size_t)(base + m0 + r0) * I_DIM + lcol;
    const unsigned short* Ag1 = Hg + (size_t)(base + m0 + r1) * I_DIM + lcol;
    const size_t wbase = (size_t)e * H_DIM * I_DIM;
    const unsigned short* Bg0 = w2b + wbase + (size_t)(n0 + r0) * I_DIM + lcol;
    const unsigned short* Bg1 = w2b + wbase + (size_t)(n0 + r1) * I_DIM + lcol;
    unsigned short* AsD0 = &As[(wv * 2) * 16 * BK];
    unsigned short* AsD1 = &As[(wv * 2 + 1) * 16 * BK];
    unsigned short* BsD0 = &Bs[(wv * 2) * 16 * BK];
    unsigned short* BsD1 = &Bs[(wv * 2 + 1) * 16 * BK];

    for (int kk = 0; kk < I_DIM; kk += BK) {
        glds16(Ag0 + kk, AsD0);
        glds16(Ag1 + kk, AsD1);
        glds16(Bg0 + kk, BsD0);
        glds16(Bg1 + kk, BsD1);
        __syncthreads();

        bf16x8 a[4], b[4];
#pragma unroll
        for (int im = 0; im < 4; im++)
            a[im] = ldfrag(&As[(wm * 64 + im * 16 + frow) * BK + koff]);
#pragma unroll
        for (int jn = 0; jn < 4; jn++)
            b[jn] = ldfrag(&Bs[(wn * 64 + jn * 16 + frow) * BK + koff]);
#pragma unroll
        for (int im = 0; im < 4; im++)
#pragma unroll
            for (int jn = 0; jn < 4; jn++)
                acc[im][jn] = __builtin_amdgcn_mfma_f32_16x16x32_bf16(a[im], b[jn], acc[im][jn], 0, 0, 0);
        __syncthreads();
    }

#pragma unroll
    for (int im = 0; im < 4; im++) {
        const int rb = m0 + wm * 64 + im * 16 + (lane >> 4) * 4;
#pragma unroll
        for (int jn = 0; jn < 4; jn++) {
            const int cb = n0 + wn * 64 + jn * 16 + frow;
            f32x4 v = acc[im][jn];
#pragma unroll
            for (int r = 0; r < 4; r++) {
                const int row = rb + r;
                if (row < Me) Og[(size_t)(base + row) * H_DIM + cb] = v[r];
            }
        }
    }
}

// ---------------- combine: out[t] = p0*Og[r0] + p1*Og[r1] ----------------
__global__ __launch_bounds__(256) void combine_kernel(
    const float* __restrict__ Og, const int* __restrict__ tok_row,
    const float* __restrict__ tok_w, float* __restrict__ out)
{
    const int t = blockIdx.x;
    const int c = threadIdx.x * 4;
    const int r0 = tok_row[t * 2], r1 = tok_row[t * 2 + 1];
    const float w0 = tok_w[t * 2], w1 = tok_w[t * 2 + 1];
    f32x4 a = *(const f32x4*)(Og + (size_t)r0 * H_DIM + c);
    f32x4 b = *(const f32x4*)(Og + (size_t)r1 * H_DIM + c);
    f32x4 o = a * w0 + b * w1;
    *(f32x4*)(out + (size_t)t * H_DIM + c) = o;
}

extern "C" void kernel_launch(void* const* d_in, const int* in_sizes, int n_in,
                              void* d_out, int out_size, void* d_ws, size_t ws_size,
                              hipStream_t stream) {
    const float* x  = (const float*)d_in[0];
    const float* gw = (const float*)d_in[1];
    const float* gb = (const float*)d_in[2];
    const float* w1 = (const float*)d_in[3];
    const float* w2 = (const float*)d_in[4];
    const float* w3 = (const float*)d_in[5];
    float* out = (float*)d_out;

    char* ws = (char*)d_ws;
    int* counts  = (int*)ws;                 // 8
    int* wptr    = counts + 8;               // 8
    int* offs    = wptr + 8;                 // 9
    int* tok_exp = (int*)(ws + 256);         // 2T
    int* tok_row = tok_exp + 2 * T_DIM;      // 2T
    float* tok_w = (float*)(tok_row + 2 * T_DIM); // 2T
    size_t ofs = 256 + (size_t)3 * 2 * T_DIM * 4;
    ofs = (ofs + 255) & ~(size_t)255;
    const size_t ROWS = 2 * T_DIM + 128;     // 128 rows slack for 128-tile overshoot
    const long NW = (long)E_DIM * I_DIM * H_DIM;   // w1/w3/w2 elem count (same)
    unsigned short* Xg  = (unsigned short*)(ws + ofs); ofs += ROWS * H_DIM * 2;
    unsigned short* Hg  = (unsigned short*)(ws + ofs); ofs += ROWS * I_DIM * 2;
    unsigned short* w2b = (unsigned short*)(ws + ofs); ofs += (size_t)NW * 2;
    unsigned short* w1b = (unsigned short*)(ws + ofs); ofs += (size_t)NW * 2;
    unsigned short* w3b = (unsigned short*)(ws + ofs); ofs += (size_t)NW * 2;
    // Og aliases w1b+w3b region (both dead after gemm13; re-converted every call)
    float* Og = (float*)w1b;

    const int cgrid = (int)(NW / 8 / 256);
    hipMemsetAsync(counts, 0, 64, stream);
    convert_kernel<<<cgrid, 256, 0, stream>>>(w1, w1b, NW);
    convert_kernel<<<cgrid, 256, 0, stream>>>(w3, w3b, NW);
    convert_kernel<<<cgrid, 256, 0, stream>>>(w2, w2b, NW);
    router_kernel<<<T_DIM / 4, 256, 0, stream>>>(x, gw, gb, counts, tok_exp, tok_w);
    scan_kernel<<<1, 64, 0, stream>>>(counts, offs, wptr);
    gather_kernel<<<T_DIM, 256, 0, stream>>>(x, tok_exp, wptr, tok_row, Xg);
    gemm13_kernel<<<dim3(I_DIM / 64, 64, E_DIM), 256, 0, stream>>>(Xg, w1b, w3b, offs, Hg);
    gemm2_kernel<<<dim3(H_DIM / 128, 64, E_DIM), 256, 0, stream>>>(Hg, w2b, offs, Og);
    combine_kernel<<<T_DIM, 256, 0, stream>>>(Og, tok_row, tok_w, out);
}

// Round 3
// 1198.310 us; speedup vs baseline: 1.1637x; 1.0359x over previous
//
#include <hip/hip_runtime.h>
#include <cstdint>
#include <cstddef>

#define T_DIM 8192
#define H_DIM 1024
#define I_DIM 3584
#define E_DIM 8
#define BK 32

typedef __attribute__((ext_vector_type(4))) float f32x4;
typedef __attribute__((ext_vector_type(8))) __bf16 bf16x8;
typedef __attribute__((ext_vector_type(8))) unsigned short u16x8;
typedef __attribute__((ext_vector_type(4))) unsigned short u16x4;

// fp32 -> bf16 round-to-nearest-even (finite inputs)
static __device__ inline unsigned short f2b(float f) {
    unsigned int u = __builtin_bit_cast(unsigned int, f);
    u += 0x7FFFu + ((u >> 16) & 1u);
    return (unsigned short)(u >> 16);
}

static __device__ inline bf16x8 ldfrag(const unsigned short* p) {
    return __builtin_bit_cast(bf16x8, *(const u16x8*)p);
}

// async global->LDS, 16B per lane. LDS dest is wave-uniform base + lane*16 (HW rule).
static __device__ inline void glds16(const unsigned short* g, unsigned short* l) {
    __builtin_amdgcn_global_load_lds(
        (const __attribute__((address_space(1))) void*)g,
        (__attribute__((address_space(3))) void*)l,
        16, 0, 0);
}

#define CONV_BLOCKS 14336   // NW / (256*8)

// ---------------- prep: 3x weight fp32->bf16 converts + router, one dispatch ----
__global__ __launch_bounds__(256) void prep_kernel(
    const float* __restrict__ w1, const float* __restrict__ w3,
    const float* __restrict__ w2,
    unsigned short* __restrict__ w1b, unsigned short* __restrict__ w3b,
    unsigned short* __restrict__ w2b,
    const float* __restrict__ x, const float* __restrict__ gw,
    const float* __restrict__ gb, int* __restrict__ counts,
    int* __restrict__ tok_exp, float* __restrict__ tok_w)
{
    const int b = blockIdx.x;
    if (b < 3 * CONV_BLOCKS) {
        const float* src; unsigned short* dst;
        int part = b / CONV_BLOCKS;
        if (part == 0)      { src = w1; dst = w1b; }
        else if (part == 1) { src = w3; dst = w3b; }
        else                { src = w2; dst = w2b; }
        long i = ((long)(b - part * CONV_BLOCKS) * 256 + threadIdx.x) * 8;
        f32x4 f0 = *(const f32x4*)(src + i);
        f32x4 f1 = *(const f32x4*)(src + i + 4);
        u16x8 o;
        o[0] = f2b(f0[0]); o[1] = f2b(f0[1]); o[2] = f2b(f0[2]); o[3] = f2b(f0[3]);
        o[4] = f2b(f1[0]); o[5] = f2b(f1[1]); o[6] = f2b(f1[2]); o[7] = f2b(f1[3]);
        *(u16x8*)(dst + i) = o;
        return;
    }
    // router: 4 tokens per block (1 wave each)
    const int t = (b - 3 * CONV_BLOCKS) * 4 + (threadIdx.x >> 6);
    const int lane = threadIdx.x & 63;
    const float* xp = x + (size_t)t * H_DIM;
    float xr[16];
#pragma unroll
    for (int i = 0; i < 16; i++) xr[i] = xp[lane + 64 * i];
    float lg[E_DIM];
#pragma unroll
    for (int e = 0; e < E_DIM; e++) {
        const float* gp = gw + e * H_DIM;
        float s = 0.f;
#pragma unroll
        for (int i = 0; i < 16; i++) s += xr[i] * gp[lane + 64 * i];
        for (int off = 32; off; off >>= 1) s += __shfl_xor(s, off, 64);
        lg[e] = s + gb[e];
    }
    if (lane == 0) {
        float mx = lg[0];
#pragma unroll
        for (int e = 1; e < E_DIM; e++) mx = fmaxf(mx, lg[e]);
        float p[E_DIM], sum = 0.f;
#pragma unroll
        for (int e = 0; e < E_DIM; e++) { p[e] = __expf(lg[e] - mx); sum += p[e]; }
        float inv = 1.0f / sum;
        int e0 = 0; float p0 = p[0];
#pragma unroll
        for (int e = 1; e < E_DIM; e++) if (p[e] > p0) { p0 = p[e]; e0 = e; }
        int e1 = -1; float p1 = -1.0f;
#pragma unroll
        for (int e = 0; e < E_DIM; e++) if (e != e0 && p[e] > p1) { p1 = p[e]; e1 = e; }
        tok_exp[t * 2]     = e0;
        tok_exp[t * 2 + 1] = e1;
        tok_w[t * 2]     = p0 * inv;
        tok_w[t * 2 + 1] = p1 * inv;
        atomicAdd(&counts[e0], 1);
        atomicAdd(&counts[e1], 1);
    }
}

// ---------------- exclusive scan over 8 counts ----------------
__global__ void scan_kernel(const int* __restrict__ counts,
                            int* __restrict__ offs, int* __restrict__ wptr)
{
    if (threadIdx.x == 0 && blockIdx.x == 0) {
        int acc = 0;
        for (int e = 0; e < E_DIM; e++) { offs[e] = acc; wptr[e] = acc; acc += counts[e]; }
        offs[E_DIM] = acc;
    }
}

// ---------------- gather: bf16 rows + row->(token, weight) map ----------------
__global__ __launch_bounds__(256) void gather_kernel(
    const float* __restrict__ x, const int* __restrict__ tok_exp,
    const float* __restrict__ tok_w, int* __restrict__ wptr,
    int* __restrict__ row_tok, float* __restrict__ row_w,
    unsigned short* __restrict__ Xg)
{
    const int t = blockIdx.x;
    __shared__ int rows[2];
    if (threadIdx.x < 2) {
        int e = tok_exp[t * 2 + threadIdx.x];
        int r = atomicAdd(&wptr[e], 1);
        rows[threadIdx.x] = r;
        row_tok[r] = t;
        row_w[r] = tok_w[t * 2 + threadIdx.x];
    }
    __syncthreads();
    const int c = threadIdx.x * 4;
    f32x4 v = *(const f32x4*)(x + (size_t)t * H_DIM + c);
    u16x4 b;
    b[0] = f2b(v[0]); b[1] = f2b(v[1]); b[2] = f2b(v[2]); b[3] = f2b(v[3]);
    *(u16x4*)&Xg[(size_t)rows[0] * H_DIM + c] = b;
    *(u16x4*)&Xg[(size_t)rows[1] * H_DIM + c] = b;
}

// ---------------- GEMM1: Hg = silu(Xg @ w1^T) * (Xg @ w3^T) ----------------
// m97 structure: 128M x 64N tile, dual accumulators, BK=32, unpadded LDS, glds16.
__global__ __launch_bounds__(256) void gemm13_kernel(
    const unsigned short* __restrict__ Xg, const unsigned short* __restrict__ w1b,
    const unsigned short* __restrict__ w3b, const int* __restrict__ offs,
    unsigned short* __restrict__ Hg)
{
    const int e = blockIdx.z;
    const int base = offs[e];
    const int Me = offs[e + 1] - base;
    const int m0 = blockIdx.y * 128;
    if (m0 >= Me) return;
    const int n0 = blockIdx.x * 64;
    const int tid = threadIdx.x;
    const int lane = tid & 63;
    const int wv = tid >> 6;

    __shared__ __align__(16) unsigned short As[128 * BK];
    __shared__ __align__(16) unsigned short B1s[64 * BK];
    __shared__ __align__(16) unsigned short B3s[64 * BK];

    const int wm = wv & 1;
    const int wn = wv >> 1;
    const int frow = lane & 15;
    const int koff = (lane >> 4) * 8;

    f32x4 acc1[4][2], acc3[4][2];
#pragma unroll
    for (int i = 0; i < 4; i++)
#pragma unroll
        for (int j = 0; j < 2; j++) {
            acc1[i][j] = f32x4{0.f, 0.f, 0.f, 0.f};
            acc3[i][j] = f32x4{0.f, 0.f, 0.f, 0.f};
        }

    const int lrow = lane >> 2;
    const int lcol = (lane & 3) * 8;
    const int ar0 = (wv * 2) * 16 + lrow;
    const int ar1 = (wv * 2 + 1) * 16 + lrow;
    const int br  = wv * 16 + lrow;
    const unsigned short* Ag0 = Xg + (size_t)(base + m0 + ar0) * H_DIM + lcol;
    const unsigned short* Ag1 = Xg + (size_t)(base + m0 + ar1) * H_DIM + lcol;
    const size_t wb = (size_t)e * I_DIM * H_DIM + (size_t)(n0 + br) * H_DIM + lcol;
    const unsigned short* B1g = w1b + wb;
    const unsigned short* B3g = w3b + wb;
    unsigned short* AsD0 = &As[(wv * 2) * 16 * BK];
    unsigned short* AsD1 = &As[(wv * 2 + 1) * 16 * BK];
    unsigned short* B1D = &B1s[wv * 16 * BK];
    unsigned short* B3D = &B3s[wv * 16 * BK];

    for (int kk = 0; kk < H_DIM; kk += BK) {
        glds16(Ag0 + kk, AsD0);
        glds16(Ag1 + kk, AsD1);
        glds16(B1g + kk, B1D);
        glds16(B3g + kk, B3D);
        __syncthreads();

        bf16x8 a[4], b1[2], b3[2];
#pragma unroll
        for (int im = 0; im < 4; im++)
            a[im] = ldfrag(&As[(wm * 64 + im * 16 + frow) * BK + koff]);
#pragma unroll
        for (int jn = 0; jn < 2; jn++) {
            b1[jn] = ldfrag(&B1s[(wn * 32 + jn * 16 + frow) * BK + koff]);
            b3[jn] = ldfrag(&B3s[(wn * 32 + jn * 16 + frow) * BK + koff]);
        }
#pragma unroll
        for (int im = 0; im < 4; im++)
#pragma unroll
            for (int jn = 0; jn < 2; jn++) {
                acc1[im][jn] = __builtin_amdgcn_mfma_f32_16x16x32_bf16(a[im], b1[jn], acc1[im][jn], 0, 0, 0);
                acc3[im][jn] = __builtin_amdgcn_mfma_f32_16x16x32_bf16(a[im], b3[jn], acc3[im][jn], 0, 0, 0);
            }
        __syncthreads();
    }

    // epilogue: SwiGLU, bf16 store (C layout: col=lane&15, row=(lane>>4)*4+r)
#pragma unroll
    for (int im = 0; im < 4; im++) {
        const int rb = m0 + wm * 64 + im * 16 + (lane >> 4) * 4;
#pragma unroll
        for (int jn = 0; jn < 2; jn++) {
            const int cb = n0 + wn * 32 + jn * 16 + frow;
            f32x4 v1 = acc1[im][jn], v3 = acc3[im][jn];
#pragma unroll
            for (int r = 0; r < 4; r++) {
                const int row = rb + r;
                if (row < Me) {
                    float xx = v1[r];
                    float h = (xx / (1.0f + __expf(-xx))) * v3[r];
                    Hg[(size_t)(base + row) * I_DIM + cb] = f2b(h);
                }
            }
        }
    }
}

// ---------------- GEMM2 + combine: atomic-scatter weighted rows into out ------
__global__ __launch_bounds__(256) void gemm2_kernel(
    const unsigned short* __restrict__ Hg, const unsigned short* __restrict__ w2b,
    const int* __restrict__ offs, const int* __restrict__ row_tok,
    const float* __restrict__ row_w, float* __restrict__ out)
{
    const int e = blockIdx.z;
    const int base = offs[e];
    const int Me = offs[e + 1] - base;
    const int m0 = blockIdx.y * 128;
    if (m0 >= Me) return;
    const int n0 = blockIdx.x * 128;
    const int tid = threadIdx.x;
    const int lane = tid & 63;
    const int wv = tid >> 6;

    __shared__ __align__(16) unsigned short As[128 * BK];
    __shared__ __align__(16) unsigned short Bs[128 * BK];

    const int wm = wv & 1;
    const int wn = wv >> 1;
    const int frow = lane & 15;
    const int koff = (lane >> 4) * 8;

    f32x4 acc[4][4];
#pragma unroll
    for (int i = 0; i < 4; i++)
#pragma unroll
        for (int j = 0; j < 4; j++) acc[i][j] = f32x4{0.f, 0.f, 0.f, 0.f};

    const int lrow = lane >> 2;
    const int lcol = (lane & 3) * 8;
    const int r0 = (wv * 2) * 16 + lrow;
    const int r1 = (wv * 2 + 1) * 16 + lrow;
    const unsigned short* Ag0 = Hg + (size_t)(base + m0 + r0) * I_DIM + lcol;
    const unsigned short* Ag1 = Hg + (size_t)(base + m0 + r1) * I_DIM + lcol;
    const size_t wbase = (size_t)e * H_DIM * I_DIM;
    const unsigned short* Bg0 = w2b + wbase + (size_t)(n0 + r0) * I_DIM + lcol;
    const unsigned short* Bg1 = w2b + wbase + (size_t)(n0 + r1) * I_DIM + lcol;
    unsigned short* AsD0 = &As[(wv * 2) * 16 * BK];
    unsigned short* AsD1 = &As[(wv * 2 + 1) * 16 * BK];
    unsigned short* BsD0 = &Bs[(wv * 2) * 16 * BK];
    unsigned short* BsD1 = &Bs[(wv * 2 + 1) * 16 * BK];

    for (int kk = 0; kk < I_DIM; kk += BK) {
        glds16(Ag0 + kk, AsD0);
        glds16(Ag1 + kk, AsD1);
        glds16(Bg0 + kk, BsD0);
        glds16(Bg1 + kk, BsD1);
        __syncthreads();

        bf16x8 a[4], b[4];
#pragma unroll
        for (int im = 0; im < 4; im++)
            a[im] = ldfrag(&As[(wm * 64 + im * 16 + frow) * BK + koff]);
#pragma unroll
        for (int jn = 0; jn < 4; jn++)
            b[jn] = ldfrag(&Bs[(wn * 64 + jn * 16 + frow) * BK + koff]);
#pragma unroll
        for (int im = 0; im < 4; im++)
#pragma unroll
            for (int jn = 0; jn < 4; jn++)
                acc[im][jn] = __builtin_amdgcn_mfma_f32_16x16x32_bf16(a[im], b[jn], acc[im][jn], 0, 0, 0);
        __syncthreads();
    }

    // epilogue: weighted atomic scatter (combine fused; each out elem gets 2 adds)
#pragma unroll
    for (int im = 0; im < 4; im++) {
        const int rb = m0 + wm * 64 + im * 16 + (lane >> 4) * 4;
        int tk[4]; float wt[4];
#pragma unroll
        for (int r = 0; r < 4; r++) {
            const int row = rb + r;
            if (row < Me) { tk[r] = row_tok[base + row]; wt[r] = row_w[base + row]; }
            else          { tk[r] = -1; wt[r] = 0.f; }
        }
#pragma unroll
        for (int jn = 0; jn < 4; jn++) {
            const int cb = n0 + wn * 64 + jn * 16 + frow;
            f32x4 v = acc[im][jn];
#pragma unroll
            for (int r = 0; r < 4; r++) {
                if (tk[r] >= 0)
                    atomicAdd(&out[(size_t)tk[r] * H_DIM + cb], v[r] * wt[r]);
            }
        }
    }
}

extern "C" void kernel_launch(void* const* d_in, const int* in_sizes, int n_in,
                              void* d_out, int out_size, void* d_ws, size_t ws_size,
                              hipStream_t stream) {
    const float* x  = (const float*)d_in[0];
    const float* gw = (const float*)d_in[1];
    const float* gb = (const float*)d_in[2];
    const float* w1 = (const float*)d_in[3];
    const float* w2 = (const float*)d_in[4];
    const float* w3 = (const float*)d_in[5];
    float* out = (float*)d_out;

    char* ws = (char*)d_ws;
    int* counts  = (int*)ws;                 // 8
    int* wptr    = counts + 8;               // 8
    int* offs    = wptr + 8;                 // 9
    int* tok_exp = (int*)(ws + 256);         // 2T
    int* row_tok = tok_exp + 2 * T_DIM;      // 2T
    float* tok_w = (float*)(row_tok + 2 * T_DIM); // 2T
    float* row_w = tok_w + 2 * T_DIM;        // 2T
    size_t ofs = 256 + (size_t)4 * 2 * T_DIM * 4;
    ofs = (ofs + 255) & ~(size_t)255;
    const size_t ROWS = 2 * T_DIM + 128;     // slack for 128-tile overshoot
    const long NW = (long)E_DIM * I_DIM * H_DIM;
    unsigned short* Xg  = (unsigned short*)(ws + ofs); ofs += ROWS * H_DIM * 2;
    unsigned short* Hg  = (unsigned short*)(ws + ofs); ofs += ROWS * I_DIM * 2;
    unsigned short* w2b = (unsigned short*)(ws + ofs); ofs += (size_t)NW * 2;
    unsigned short* w1b = (unsigned short*)(ws + ofs); ofs += (size_t)NW * 2;
    unsigned short* w3b = (unsigned short*)(ws + ofs); ofs += (size_t)NW * 2;

    hipMemsetAsync(counts, 0, 64, stream);
    hipMemsetAsync(out, 0, (size_t)out_size * sizeof(float), stream);
    prep_kernel<<<3 * CONV_BLOCKS + T_DIM / 4, 256, 0, stream>>>(
        w1, w3, w2, w1b, w3b, w2b, x, gw, gb, counts, tok_exp, tok_w);
    scan_kernel<<<1, 64, 0, stream>>>(counts, offs, wptr);
    gather_kernel<<<T_DIM, 256, 0, stream>>>(x, tok_exp, tok_w, wptr, row_tok, row_w, Xg);
    gemm13_kernel<<<dim3(I_DIM / 64, 64, E_DIM), 256, 0, stream>>>(Xg, w1b, w3b, offs, Hg);
    gemm2_kernel<<<dim3(H_DIM / 128, 64, E_DIM), 256, 0, stream>>>(Hg, w2b, offs, row_tok, row_w, out);
}